// Round 17
// baseline (45.641 us; speedup 1.0000x reference)
//
#include <hip/hip_runtime.h>
#include <math.h>

// Problem constants (match reference)
#define BATCH 4
#define LSEQ  4096
#define DCH   512
#define NST   16
#define DBLK  8                    // d-channels per block
#define TCH   32                   // chunk length along L
#define CCH   (LSEQ / TCH)         // 128 chunks
#define TPB   (DBLK * CCH)         // 1024 threads per block
#define NCHAIN (DBLK * NST)        // 128 (d,n) chains per block
#define CSTR  (NCHAIN + 4)         // 132: all LDS accesses <=2-way (free)
#define SEG   16                   // chunks per P2 segment
#define NSEG  (CCH / SEG)          // 8 segments

// One block = (batch b, 8-channel slice), full L in-block, one launch.
// g-space recurrence: g = g*dA + x;  y = dot(g, dB).
// R17 deltas vs R13 (both mechanism-backed, else identical):
//  (1) x loads issued BEFORE the expf prologue -> L2 latency hides under
//      the transcendental chain instead of stalling at barrier 1.
//  (2) y written with nontemporal stores -> y doesn't evict x from L3
//      (R13 showed FETCH=16.6MiB re-fetch of x each replay).
__global__ __launch_bounds__(TPB) void mamba_one(
    const float* __restrict__ x, const float* __restrict__ A,
    const float* __restrict__ Bm, const float* __restrict__ delta,
    float* __restrict__ y)
{
    __shared__ float v[CCH * CSTR];      // 128 x 132 x 4B = 67.6 KB
    __shared__ float aT[NCHAIN];         // dA^TCH per chain
    __shared__ float tot[NSEG * NCHAIN]; // 8 x 128 x 4B = 4 KB

    // XCD swizzle: consecutive logical blocks (adjacent d-groups, shared
    // x cache lines) land on the same XCD's L2. 256 = 8 XCD x 32.
    const int lb   = (blockIdx.x & 7) * 32 + (blockIdx.x >> 3);  // 0..255
    const int b    = lb >> 6;                // 0..3
    const int dgrp = lb & 63;                // 0..63
    const int d0   = dgrp * DBLK;

    const int tid = threadIdx.x;
    const int d   = tid & (DBLK - 1);        // 0..7
    const int c   = tid >> 3;                // 0..127

    const int dg   = d0 + d;                 // global channel
    const float dl = delta[dg];

    // ---- (1) issue ALL x loads FIRST; exp prologue runs under them ----
    const float* xp = x + ((size_t)b * LSEQ + (size_t)c * TCH) * DCH + dg;
    float xv[TCH];
#pragma unroll
    for (int t = 0; t < TCH; ++t)
        xv[t] = xp[(size_t)t * DCH];      // 32 independent loads in flight

    float dA[NST], g[NST];
    const float4* Arow = (const float4*)(A + dg * NST);
#pragma unroll
    for (int q = 0; q < 4; ++q) {
        float4 a4 = Arow[q];
        dA[4*q+0] = expf(dl * a4.x);
        dA[4*q+1] = expf(dl * a4.y);
        dA[4*q+2] = expf(dl * a4.z);
        dA[4*q+3] = expf(dl * a4.w);
    }
#pragma unroll
    for (int n = 0; n < NST; ++n) g[n] = 0.f;

    // chain decay table: thread (d, c=n<16) publishes dA[n]^32 for chain n*8+d
    if (c < NST) {
        float p = dA[c];
#pragma unroll
        for (int k = 0; k < 5; ++k) p *= p;   // ^32
        aT[c * DBLK + d] = p;
    }

    // ---- Phase 1: local g-scan (g0 = 0); exit g -> v ----
#pragma unroll
    for (int t = 0; t < TCH; ++t) {
#pragma unroll
        for (int n = 0; n < NST; ++n)
            g[n] = fmaf(g[n], dA[n], xv[t]);
    }
#pragma unroll
    for (int n = 0; n < NST; ++n)
        v[c * CSTR + (n * DBLK + d)] = g[n];

    // Pin xv in registers (before the barrier): opaque def prevents the
    // compiler from rematerializing the loads after P2 (R12/R13 evidence).
#pragma unroll
    for (int t = 0; t < TCH; ++t)
        asm volatile("" : "+v"(xv[t]));

    __syncthreads();

    // ---- Phase 2: work-efficient scan along c (128 chains x 128 chunks) ----
    {
        const int ch = tid & (NCHAIN - 1);   // chain (lane-consecutive)
        const int s  = tid >> 7;             // segment 0..7
        const float aTc = aT[ch];
        float aT16 = aTc;
#pragma unroll
        for (int k = 0; k < 4; ++k) aT16 *= aT16;   // (dA^32)^16

        // P2a: register inclusive scan of this 16-chunk segment
        float sv[SEG];
#pragma unroll
        for (int i = 0; i < SEG; ++i)
            sv[i] = v[(s * SEG + i) * CSTR + ch];
#pragma unroll
        for (int i = 1; i < SEG; ++i)
            sv[i] = fmaf(sv[i-1], aTc, sv[i]);

        tot[s * NCHAIN + ch] = sv[SEG - 1];
        __syncthreads();

        // P2b: carry-in = decayed scan of previous segment totals
        float pfx = 0.f;
#pragma unroll
        for (int j = 0; j < NSEG - 1; ++j) {
            float Tj = tot[j * NCHAIN + ch];
            float np = fmaf(pfx, aT16, Tj);
            pfx = (j < s) ? np : pfx;
        }

        // P2c: apply carry with powers of aTc, write back inclusive values
        float w = aTc;
#pragma unroll
        for (int i = 0; i < SEG; ++i) {
            v[(s * SEG + i) * CSTR + ch] = fmaf(pfx, w, sv[i]);
            w *= aTc;
        }
        __syncthreads();
    }

    // ---- Phase 3: entry = v[c-1]; replay from registers; y = dot(g, dB) ----
#pragma unroll
    for (int n = 0; n < NST; ++n) {
        int cm = (c > 0) ? (c - 1) : 0;
        float e = v[cm * CSTR + (n * DBLK + d)];
        g[n] = (c > 0) ? e : 0.f;
    }

    float dB[NST];
    const float4* Brow = (const float4*)(Bm + dg * NST);
#pragma unroll
    for (int q = 0; q < 4; ++q) {
        float4 b4 = Brow[q];
        dB[4*q+0] = dl * b4.x;
        dB[4*q+1] = dl * b4.y;
        dB[4*q+2] = dl * b4.z;
        dB[4*q+3] = dl * b4.w;
    }

    float* yp = y + ((size_t)b * LSEQ + (size_t)c * TCH) * DCH + dg;
#pragma unroll
    for (int t = 0; t < TCH; ++t) {
#pragma unroll
        for (int n = 0; n < NST; ++n)
            g[n] = fmaf(g[n], dA[n], xv[t]);
        float a0 = 0.f, a1 = 0.f, a2 = 0.f, a3 = 0.f;
#pragma unroll
        for (int n = 0; n < NST; n += 4) {
            a0 = fmaf(g[n+0], dB[n+0], a0);
            a1 = fmaf(g[n+1], dB[n+1], a1);
            a2 = fmaf(g[n+2], dB[n+2], a2);
            a3 = fmaf(g[n+3], dB[n+3], a3);
        }
        // (2) nontemporal: y is write-once, keep L3 for x
        __builtin_nontemporal_store((a0 + a1) + (a2 + a3), &yp[(size_t)t * DCH]);
    }
}

extern "C" void kernel_launch(void* const* d_in, const int* in_sizes, int n_in,
                              void* d_out, int out_size, void* d_ws, size_t ws_size,
                              hipStream_t stream) {
    const float* x     = (const float*)d_in[0];   // (B, L, D)
    const float* A     = (const float*)d_in[1];   // (D, N)
    const float* Bm    = (const float*)d_in[2];   // (D, N)
    const float* delta = (const float*)d_in[3];   // (D,)
    float*       y     = (float*)d_out;           // (B, L, D)

    const int nblocks = BATCH * (DCH / DBLK);     // 256 blocks, 1 per CU
    mamba_one<<<nblocks, TPB, 0, stream>>>(x, A, Bm, delta, y);
}

// Round 18
// 24.562 us; speedup vs baseline: 1.8582x; 1.8582x over previous
//
#include <hip/hip_runtime.h>
#include <math.h>

// Problem constants (match reference)
#define BATCH 4
#define LSEQ  4096
#define DCH   512
#define NST   16
#define DBLK  8                    // d-channels per block
#define TCH   32                   // chunk length along L
#define CCH   (LSEQ / TCH)         // 128 chunks
#define TPB   (DBLK * CCH)         // 1024 threads per block
#define NCHAIN (DBLK * NST)        // 128 (d,n) chains per block
#define CSTR  (NCHAIN + 4)         // 132: all LDS accesses <=2-way (free)
#define SEG   16                   // chunks per P2 segment
#define NSEG  (CCH / SEG)          // 8 segments

// One block = (batch b, 8-channel slice), full L in-block, one launch.
// g-space recurrence: g = g*dA + x;  y = dot(g, dB).
// LDS v layout: v[chunk][chain], chain = n*DBLK + d, stride CSTR=132.
// R18 = R13 exactly, except P2c writes EXCLUSIVE (entry) states shifted
// +1 chunk (seg0 zeroes chunk 0; last write dropped) so P3's entry read
// is a plain load with no per-element select. (R17's nontemporal-store
// and load-reorder both reverted: nontemporal cost +21us of HBM partial-
// line writes per replay.)
__global__ __launch_bounds__(TPB) void mamba_one(
    const float* __restrict__ x, const float* __restrict__ A,
    const float* __restrict__ Bm, const float* __restrict__ delta,
    float* __restrict__ y)
{
    __shared__ float v[CCH * CSTR];      // 128 x 132 x 4B = 67.6 KB
    __shared__ float aT[NCHAIN];         // dA^TCH per chain
    __shared__ float tot[NSEG * NCHAIN]; // 8 x 128 x 4B = 4 KB

    // XCD swizzle: consecutive logical blocks (adjacent d-groups, shared
    // x cache lines) land on the same XCD's L2. 256 = 8 XCD x 32.
    const int lb   = (blockIdx.x & 7) * 32 + (blockIdx.x >> 3);  // 0..255
    const int b    = lb >> 6;                // 0..3
    const int dgrp = lb & 63;                // 0..63
    const int d0   = dgrp * DBLK;

    const int tid = threadIdx.x;
    const int d   = tid & (DBLK - 1);        // 0..7
    const int c   = tid >> 3;                // 0..127

    const int dg   = d0 + d;                 // global channel
    const float dl = delta[dg];

    float dA[NST], g[NST];
    const float4* Arow = (const float4*)(A + dg * NST);
#pragma unroll
    for (int q = 0; q < 4; ++q) {
        float4 a4 = Arow[q];
        dA[4*q+0] = expf(dl * a4.x);
        dA[4*q+1] = expf(dl * a4.y);
        dA[4*q+2] = expf(dl * a4.z);
        dA[4*q+3] = expf(dl * a4.w);
    }
#pragma unroll
    for (int n = 0; n < NST; ++n) g[n] = 0.f;

    // chain decay table: thread (d, c=n<16) publishes dA[n]^32 for chain n*8+d
    if (c < NST) {
        float p = dA[c];
#pragma unroll
        for (int k = 0; k < 5; ++k) p *= p;   // ^32
        aT[c * DBLK + d] = p;
    }

    // ---- Phase 1: issue ALL x loads, then g-scan; exit g -> v ----
    const float* xp = x + ((size_t)b * LSEQ + (size_t)c * TCH) * DCH + dg;
    float xv[TCH];
#pragma unroll
    for (int t = 0; t < TCH; ++t)
        xv[t] = xp[(size_t)t * DCH];      // 32 independent loads in flight

#pragma unroll
    for (int t = 0; t < TCH; ++t) {
#pragma unroll
        for (int n = 0; n < NST; ++n)
            g[n] = fmaf(g[n], dA[n], xv[t]);
    }
#pragma unroll
    for (int n = 0; n < NST; ++n)
        v[c * CSTR + (n * DBLK + d)] = g[n];

    // Pin xv in registers (before the barrier): opaque def prevents the
    // compiler from rematerializing the loads after P2 (R12/R13 evidence).
#pragma unroll
    for (int t = 0; t < TCH; ++t)
        asm volatile("" : "+v"(xv[t]));

    __syncthreads();

    // ---- Phase 2: work-efficient scan along c (128 chains x 128 chunks) ----
    {
        const int ch = tid & (NCHAIN - 1);   // chain (lane-consecutive)
        const int s  = tid >> 7;             // segment 0..7
        const float aTc = aT[ch];
        float aT16 = aTc;
#pragma unroll
        for (int k = 0; k < 4; ++k) aT16 *= aT16;   // (dA^32)^16

        // P2a: register inclusive scan of this 16-chunk segment
        float sv[SEG];
#pragma unroll
        for (int i = 0; i < SEG; ++i)
            sv[i] = v[(s * SEG + i) * CSTR + ch];
#pragma unroll
        for (int i = 1; i < SEG; ++i)
            sv[i] = fmaf(sv[i-1], aTc, sv[i]);

        tot[s * NCHAIN + ch] = sv[SEG - 1];
        __syncthreads();

        // P2b: carry-in = decayed scan of previous segment totals
        float pfx = 0.f;
#pragma unroll
        for (int j = 0; j < NSEG - 1; ++j) {
            float Tj = tot[j * NCHAIN + ch];
            float np = fmaf(pfx, aT16, Tj);
            pfx = (j < s) ? np : pfx;
        }

        // P2c: write EXCLUSIVE (entry) states, shifted +1 chunk.
        // entry[c] = inclusive[c-1]; seg 0 also zeroes chunk 0; the
        // would-be write to chunk 128 (s=7,i=15) is dropped.
        if (s == 0)
            v[ch] = 0.f;                      // chunk 0 entry = 0
        float w = aTc;
#pragma unroll
        for (int i = 0; i < SEG; ++i) {
            float inc = fmaf(pfx, w, sv[i]);  // inclusive value of chunk s*16+i
            if (s * SEG + i + 1 < CCH)
                v[(s * SEG + i + 1) * CSTR + ch] = inc;
            w *= aTc;
        }
        __syncthreads();
    }

    // ---- Phase 3: entry = v[c] (pre-shifted); replay; y = dot(g, dB) ----
#pragma unroll
    for (int n = 0; n < NST; ++n)
        g[n] = v[c * CSTR + (n * DBLK + d)];

    float dB[NST];
    const float4* Brow = (const float4*)(Bm + dg * NST);
#pragma unroll
    for (int q = 0; q < 4; ++q) {
        float4 b4 = Brow[q];
        dB[4*q+0] = dl * b4.x;
        dB[4*q+1] = dl * b4.y;
        dB[4*q+2] = dl * b4.z;
        dB[4*q+3] = dl * b4.w;
    }

    float* yp = y + ((size_t)b * LSEQ + (size_t)c * TCH) * DCH + dg;
#pragma unroll
    for (int t = 0; t < TCH; ++t) {
#pragma unroll
        for (int n = 0; n < NST; ++n)
            g[n] = fmaf(g[n], dA[n], xv[t]);
        float a0 = 0.f, a1 = 0.f, a2 = 0.f, a3 = 0.f;
#pragma unroll
        for (int n = 0; n < NST; n += 4) {
            a0 = fmaf(g[n+0], dB[n+0], a0);
            a1 = fmaf(g[n+1], dB[n+1], a1);
            a2 = fmaf(g[n+2], dB[n+2], a2);
            a3 = fmaf(g[n+3], dB[n+3], a3);
        }
        yp[(size_t)t * DCH] = (a0 + a1) + (a2 + a3);
    }
}

extern "C" void kernel_launch(void* const* d_in, const int* in_sizes, int n_in,
                              void* d_out, int out_size, void* d_ws, size_t ws_size,
                              hipStream_t stream) {
    const float* x     = (const float*)d_in[0];   // (B, L, D)
    const float* A     = (const float*)d_in[1];   // (D, N)
    const float* Bm    = (const float*)d_in[2];   // (D, N)
    const float* delta = (const float*)d_in[3];   // (D,)
    float*       y     = (float*)d_out;           // (B, L, D)

    const int nblocks = BATCH * (DCH / DBLK);     // 256 blocks, 1 per CU
    mamba_one<<<nblocks, TPB, 0, stream>>>(x, A, Bm, delta, y);
}

// Round 19
// 24.307 us; speedup vs baseline: 1.8777x; 1.0105x over previous
//
#include <hip/hip_runtime.h>
#include <math.h>

// Problem constants (match reference)
#define BATCH 4
#define LSEQ  4096
#define DCH   512
#define NST   16
#define DBLK  8                    // d-channels per block
#define TCH   32                   // chunk length along L
#define CCH   (LSEQ / TCH)         // 128 chunks
#define TPB   (DBLK * CCH)         // 1024 threads per block
#define NCHAIN (DBLK * NST)        // 128 (d,n) chains per block
#define CSTR  (NCHAIN + 4)         // 132: all LDS accesses <=2-way (free)
#define SEG   16                   // chunks per P2 segment
#define NSEG  (CCH / SEG)          // 8 segments

// One block = (batch b, 8-channel slice), full L in-block, one launch.
// g-space recurrence: g = g*dA + x;  y = dot(g, dB).
// R19 = R13 exactly, except P3 uses the factored dot:
//   dot(g_t, dB) = dot(g_{t-1}, dA*dB) + x_t * sum(dB)
// so the per-step dot reads g BEFORE the update -> the dot stream and the
// g-update stream are independent (2x schedulable ILP in the longest phase),
// identical op count.
__global__ __launch_bounds__(TPB) void mamba_one(
    const float* __restrict__ x, const float* __restrict__ A,
    const float* __restrict__ Bm, const float* __restrict__ delta,
    float* __restrict__ y)
{
    __shared__ float v[CCH * CSTR];      // 128 x 132 x 4B = 67.6 KB
    __shared__ float aT[NCHAIN];         // dA^TCH per chain
    __shared__ float tot[NSEG * NCHAIN]; // 8 x 128 x 4B = 4 KB

    // XCD swizzle: consecutive logical blocks (adjacent d-groups, shared
    // x cache lines) land on the same XCD's L2. 256 = 8 XCD x 32.
    const int lb   = (blockIdx.x & 7) * 32 + (blockIdx.x >> 3);  // 0..255
    const int b    = lb >> 6;                // 0..3
    const int dgrp = lb & 63;                // 0..63
    const int d0   = dgrp * DBLK;

    const int tid = threadIdx.x;
    const int d   = tid & (DBLK - 1);        // 0..7
    const int c   = tid >> 3;                // 0..127

    const int dg   = d0 + d;                 // global channel
    const float dl = delta[dg];

    float dA[NST], g[NST];
    const float4* Arow = (const float4*)(A + dg * NST);
#pragma unroll
    for (int q = 0; q < 4; ++q) {
        float4 a4 = Arow[q];
        dA[4*q+0] = expf(dl * a4.x);
        dA[4*q+1] = expf(dl * a4.y);
        dA[4*q+2] = expf(dl * a4.z);
        dA[4*q+3] = expf(dl * a4.w);
    }
#pragma unroll
    for (int n = 0; n < NST; ++n) g[n] = 0.f;

    // chain decay table: thread (d, c=n<16) publishes dA[n]^32 for chain n*8+d
    if (c < NST) {
        float p = dA[c];
#pragma unroll
        for (int k = 0; k < 5; ++k) p *= p;   // ^32
        aT[c * DBLK + d] = p;
    }

    // ---- Phase 1: issue ALL x loads, then g-scan; exit g -> v ----
    const float* xp = x + ((size_t)b * LSEQ + (size_t)c * TCH) * DCH + dg;
    float xv[TCH];
#pragma unroll
    for (int t = 0; t < TCH; ++t)
        xv[t] = xp[(size_t)t * DCH];      // 32 independent loads in flight

#pragma unroll
    for (int t = 0; t < TCH; ++t) {
#pragma unroll
        for (int n = 0; n < NST; ++n)
            g[n] = fmaf(g[n], dA[n], xv[t]);
    }
#pragma unroll
    for (int n = 0; n < NST; ++n)
        v[c * CSTR + (n * DBLK + d)] = g[n];

    // Pin xv in registers (before the barrier): opaque def prevents the
    // compiler from rematerializing the loads after P2 (R12/R13 evidence).
#pragma unroll
    for (int t = 0; t < TCH; ++t)
        asm volatile("" : "+v"(xv[t]));

    __syncthreads();

    // ---- Phase 2: work-efficient scan along c (128 chains x 128 chunks) ----
    {
        const int ch = tid & (NCHAIN - 1);   // chain (lane-consecutive)
        const int s  = tid >> 7;             // segment 0..7
        const float aTc = aT[ch];
        float aT16 = aTc;
#pragma unroll
        for (int k = 0; k < 4; ++k) aT16 *= aT16;   // (dA^32)^16

        // P2a: register inclusive scan of this 16-chunk segment
        float sv[SEG];
#pragma unroll
        for (int i = 0; i < SEG; ++i)
            sv[i] = v[(s * SEG + i) * CSTR + ch];
#pragma unroll
        for (int i = 1; i < SEG; ++i)
            sv[i] = fmaf(sv[i-1], aTc, sv[i]);

        tot[s * NCHAIN + ch] = sv[SEG - 1];
        __syncthreads();

        // P2b: carry-in = decayed scan of previous segment totals
        float pfx = 0.f;
#pragma unroll
        for (int j = 0; j < NSEG - 1; ++j) {
            float Tj = tot[j * NCHAIN + ch];
            float np = fmaf(pfx, aT16, Tj);
            pfx = (j < s) ? np : pfx;
        }

        // P2c: apply carry with powers of aTc, write back inclusive values
        float w = aTc;
#pragma unroll
        for (int i = 0; i < SEG; ++i) {
            v[(s * SEG + i) * CSTR + ch] = fmaf(pfx, w, sv[i]);
            w *= aTc;
        }
        __syncthreads();
    }

    // ---- Phase 3: entry = v[c-1]; replay with factored dot ----
#pragma unroll
    for (int n = 0; n < NST; ++n) {
        int cm = (c > 0) ? (c - 1) : 0;
        float e = v[cm * CSTR + (n * DBLK + d)];
        g[n] = (c > 0) ? e : 0.f;
    }

    // u = dA*dB (pre-update dot weights), S = sum(dB)
    float u[NST];
    float S = 0.f;
    {
        const float4* Brow = (const float4*)(Bm + dg * NST);
#pragma unroll
        for (int q = 0; q < 4; ++q) {
            float4 b4 = Brow[q];
            float b0 = dl * b4.x, b1 = dl * b4.y, b2 = dl * b4.z, b3 = dl * b4.w;
            u[4*q+0] = dA[4*q+0] * b0;
            u[4*q+1] = dA[4*q+1] * b1;
            u[4*q+2] = dA[4*q+2] * b2;
            u[4*q+3] = dA[4*q+3] * b3;
            S += (b0 + b1) + (b2 + b3);
        }
    }

    float* yp = y + ((size_t)b * LSEQ + (size_t)c * TCH) * DCH + dg;
#pragma unroll
    for (int t = 0; t < TCH; ++t) {
        // dot stream: reads g BEFORE the update (independent of it)
        float a0 = 0.f, a1 = 0.f, a2 = 0.f, a3 = 0.f;
#pragma unroll
        for (int n = 0; n < NST; n += 4) {
            a0 = fmaf(g[n+0], u[n+0], a0);
            a1 = fmaf(g[n+1], u[n+1], a1);
            a2 = fmaf(g[n+2], u[n+2], a2);
            a3 = fmaf(g[n+3], u[n+3], a3);
        }
        // update stream: independent of the dot above
#pragma unroll
        for (int n = 0; n < NST; ++n)
            g[n] = fmaf(g[n], dA[n], xv[t]);
        yp[(size_t)t * DCH] = fmaf(xv[t], S, (a0 + a1) + (a2 + a3));
    }
}

extern "C" void kernel_launch(void* const* d_in, const int* in_sizes, int n_in,
                              void* d_out, int out_size, void* d_ws, size_t ws_size,
                              hipStream_t stream) {
    const float* x     = (const float*)d_in[0];   // (B, L, D)
    const float* A     = (const float*)d_in[1];   // (D, N)
    const float* Bm    = (const float*)d_in[2];   // (D, N)
    const float* delta = (const float*)d_in[3];   // (D,)
    float*       y     = (float*)d_out;           // (B, L, D)

    const int nblocks = BATCH * (DCH / DBLK);     // 256 blocks, 1 per CU
    mamba_one<<<nblocks, TPB, 0, stream>>>(x, A, Bm, delta, y);
}